// Round 8
// baseline (459.401 us; speedup 1.0000x reference)
//
#include <hip/hip_runtime.h>
#include <hip/hip_bf16.h>
#include <cstdint>

typedef __bf16 bf16x8 __attribute__((ext_vector_type(8)));
typedef float f32x4 __attribute__((ext_vector_type(4)));

static __device__ __forceinline__ float lrelu(float x) { return x > 0.f ? x : 0.2f * x; }
static __device__ __forceinline__ float bflo(unsigned v) { return __uint_as_float(v << 16); }
static __device__ __forceinline__ float bfhi(unsigned v) { return __uint_as_float(v & 0xffff0000u); }
static __device__ __forceinline__ float bf1(unsigned short v) { return __uint_as_float(((unsigned)v) << 16); }
static __device__ __forceinline__ unsigned short f2bf(float f) {
  unsigned u = __float_as_uint(f);
  u += 0x7fffu + ((u >> 16) & 1u);
  return (unsigned short)(u >> 16);
}

// ---------------------------------------------------------------------------
// gemm256: C[M,256] = A[M,256](fp32) @ W(256x256, pre-transposed bf16).
// BM=128, full 256 cols per block: B staged per 128-col half inside k-loop,
// so the fp32 A tile is read ONCE (halves A traffic vs grid-y=2).
// AL: fuse per-head attention logits into epilogue.
// ---------------------------------------------------------------------------
template <bool BIAS, bool RELU, bool AL>
__global__ __launch_bounds__(256) void gemm256(
    const float* __restrict__ A, const unsigned short* __restrict__ Bt,
    const float* __restrict__ bias, unsigned short* __restrict__ C, int M,
    const float* __restrict__ asrc, const float* __restrict__ adst,
    float* __restrict__ als, float* __restrict__ ald) {
  constexpr int LDA = 72;
  __shared__ __align__(16) unsigned short Al[128 * LDA];
  __shared__ __align__(16) unsigned short Bl[128 * LDA];
  const int t = threadIdx.x;
  const int w = t >> 6, lane = t & 63;
  const int quad = lane >> 4, l15 = lane & 15;
  const int row0 = blockIdx.x * 128;
  const int wrow0 = (w >> 1) * 64;
  const int wcol0 = (w & 1) * 64;

  f32x4 acc[2][4][4];
#pragma unroll
  for (int p = 0; p < 2; ++p)
#pragma unroll
    for (int i = 0; i < 4; ++i)
#pragma unroll
      for (int j = 0; j < 4; ++j) acc[p][i][j] = (f32x4){0.f, 0.f, 0.f, 0.f};

  for (int k0 = 0; k0 < 256; k0 += 64) {
    // stage A: 128 rows x 64 k, fp32 -> bf16
#pragma unroll
    for (int ci = 0; ci < 4; ++ci) {
      int id = ci * 256 + t;
      int r = id >> 3, cq = id & 7;
      int gr = row0 + r;
      uint4 pack = make_uint4(0, 0, 0, 0);
      if (gr < M) {
        const float* ap = A + (size_t)gr * 256 + k0 + cq * 8;
        float4 f0 = *(const float4*)ap;
        float4 f1 = *(const float4*)(ap + 4);
        pack.x = (unsigned)f2bf(f0.x) | ((unsigned)f2bf(f0.y) << 16);
        pack.y = (unsigned)f2bf(f0.z) | ((unsigned)f2bf(f0.w) << 16);
        pack.z = (unsigned)f2bf(f1.x) | ((unsigned)f2bf(f1.y) << 16);
        pack.w = (unsigned)f2bf(f1.z) | ((unsigned)f2bf(f1.w) << 16);
      }
      *(uint4*)&Al[r * LDA + cq * 8] = pack;
    }
#pragma unroll
    for (int ph = 0; ph < 2; ++ph) {
      if (ph) __syncthreads();  // drain mfma of previous half before Bl overwrite
#pragma unroll
      for (int ci = 0; ci < 4; ++ci) {
        int id = ci * 256 + t;
        int r = id >> 3, cq = id & 7;
        *(uint4*)&Bl[r * LDA + cq * 8] =
            *(const uint4*)(Bt + (size_t)(ph * 128 + r) * 256 + k0 + cq * 8);
      }
      __syncthreads();
#pragma unroll
      for (int ks = 0; ks < 64; ks += 32) {
        bf16x8 af[4], bfr[4];
#pragma unroll
        for (int i = 0; i < 4; ++i)
          af[i] = *(const bf16x8*)&Al[(wrow0 + i * 16 + l15) * LDA + ks + quad * 8];
#pragma unroll
        for (int j = 0; j < 4; ++j)
          bfr[j] = *(const bf16x8*)&Bl[(wcol0 + j * 16 + l15) * LDA + ks + quad * 8];
#pragma unroll
        for (int i = 0; i < 4; ++i)
#pragma unroll
          for (int j = 0; j < 4; ++j)
            acc[ph][i][j] =
                __builtin_amdgcn_mfma_f32_16x16x32_bf16(af[i], bfr[j], acc[ph][i][j], 0, 0, 0);
      }
    }
    __syncthreads();
  }

  if (AL) {
#pragma unroll
    for (int ph = 0; ph < 2; ++ph) {
      int hidx = ph * 2 + (wcol0 >> 6);
      float av[4], dv[4];
#pragma unroll
      for (int j = 0; j < 4; ++j) {
        av[j] = asrc[hidx * 64 + j * 16 + l15];
        dv[j] = adst[hidx * 64 + j * 16 + l15];
      }
#pragma unroll
      for (int i = 0; i < 4; ++i) {
#pragma unroll
        for (int r = 0; r < 4; ++r) {
          float ps = acc[ph][i][0][r] * av[0] + acc[ph][i][1][r] * av[1] +
                     acc[ph][i][2][r] * av[2] + acc[ph][i][3][r] * av[3];
          float pd = acc[ph][i][0][r] * dv[0] + acc[ph][i][1][r] * dv[1] +
                     acc[ph][i][2][r] * dv[2] + acc[ph][i][3][r] * dv[3];
#pragma unroll
          for (int o = 8; o; o >>= 1) {
            ps += __shfl_xor(ps, o, 64);
            pd += __shfl_xor(pd, o, 64);
          }
          int row = row0 + wrow0 + i * 16 + quad * 4 + r;
          if (l15 == 0 && row < M) {
            als[row * 4 + hidx] = ps;
            ald[row * 4 + hidx] = pd;
          }
        }
      }
    }
  }

#pragma unroll
  for (int ph = 0; ph < 2; ++ph) {
#pragma unroll
    for (int i = 0; i < 4; ++i) {
#pragma unroll
      for (int j = 0; j < 4; ++j) {
        int col = ph * 128 + wcol0 + j * 16 + l15;
        float bv = BIAS ? bias[col] : 0.f;
#pragma unroll
        for (int r = 0; r < 4; ++r) {
          int row = row0 + wrow0 + i * 16 + quad * 4 + r;
          if (row < M) {
            float v = acc[ph][i][j][r] + bv;
            if (RELU) v = fmaxf(v, 0.f);
            C[(size_t)row * 256 + col] = f2bf(v);
          }
        }
      }
    }
  }
}

// ---------------------------------------------------------------------------
// gemm_mfma (BN=64): C[M,64] = A[M,256](bf16) @ W(64x256 pre-transposed).
// ---------------------------------------------------------------------------
template <bool BIAS, bool OUTBF, bool AL>
__global__ __launch_bounds__(256) void gemm64(
    const unsigned short* __restrict__ Av, const unsigned short* __restrict__ Bt,
    const float* __restrict__ bias, void* __restrict__ Cv, int M,
    const float* __restrict__ asrc, const float* __restrict__ adst,
    float* __restrict__ als, float* __restrict__ ald) {
  constexpr int LDA = 72;
  __shared__ __align__(16) unsigned short Al[128 * LDA];
  __shared__ __align__(16) unsigned short Bl[64 * LDA];
  const int t = threadIdx.x;
  const int w = t >> 6, lane = t & 63;
  const int quad = lane >> 4, l15 = lane & 15;
  const int row0 = blockIdx.x * 128;
  const int wrow0 = w * 32;

  f32x4 acc[2][4];
#pragma unroll
  for (int i = 0; i < 2; ++i)
#pragma unroll
    for (int j = 0; j < 4; ++j) acc[i][j] = (f32x4){0.f, 0.f, 0.f, 0.f};

  for (int k0 = 0; k0 < 256; k0 += 64) {
#pragma unroll
    for (int ci = 0; ci < 4; ++ci) {
      int id = ci * 256 + t;
      int r = id >> 3, cq = id & 7;
      int gr = row0 + r;
      uint4 pack = make_uint4(0, 0, 0, 0);
      if (gr < M)
        pack = *(const uint4*)(Av + (size_t)gr * 256 + k0 + cq * 8);
      *(uint4*)&Al[r * LDA + cq * 8] = pack;
    }
#pragma unroll
    for (int ci = 0; ci < 2; ++ci) {
      int id = ci * 256 + t;
      int r = id >> 3, cq = id & 7;
      *(uint4*)&Bl[r * LDA + cq * 8] =
          *(const uint4*)(Bt + (size_t)r * 256 + k0 + cq * 8);
    }
    __syncthreads();
#pragma unroll
    for (int ks = 0; ks < 64; ks += 32) {
      bf16x8 af[2], bfr[4];
#pragma unroll
      for (int i = 0; i < 2; ++i)
        af[i] = *(const bf16x8*)&Al[(wrow0 + i * 16 + l15) * LDA + ks + quad * 8];
#pragma unroll
      for (int j = 0; j < 4; ++j)
        bfr[j] = *(const bf16x8*)&Bl[(j * 16 + l15) * LDA + ks + quad * 8];
#pragma unroll
      for (int i = 0; i < 2; ++i)
#pragma unroll
        for (int j = 0; j < 4; ++j)
          acc[i][j] = __builtin_amdgcn_mfma_f32_16x16x32_bf16(af[i], bfr[j], acc[i][j], 0, 0, 0);
    }
    __syncthreads();
  }

  if (AL) {
    float av[4], dv[4];
#pragma unroll
    for (int j = 0; j < 4; ++j) {
      av[j] = asrc[j * 16 + l15];
      dv[j] = adst[j * 16 + l15];
    }
#pragma unroll
    for (int i = 0; i < 2; ++i) {
#pragma unroll
      for (int r = 0; r < 4; ++r) {
        float ps = acc[i][0][r] * av[0] + acc[i][1][r] * av[1] +
                   acc[i][2][r] * av[2] + acc[i][3][r] * av[3];
        float pd = acc[i][0][r] * dv[0] + acc[i][1][r] * dv[1] +
                   acc[i][2][r] * dv[2] + acc[i][3][r] * dv[3];
#pragma unroll
        for (int o = 8; o; o >>= 1) {
          ps += __shfl_xor(ps, o, 64);
          pd += __shfl_xor(pd, o, 64);
        }
        int row = row0 + wrow0 + i * 16 + quad * 4 + r;
        if (l15 == 0 && row < M) {
          als[row] = ps;
          ald[row] = pd;
        }
      }
    }
  }

#pragma unroll
  for (int i = 0; i < 2; ++i) {
#pragma unroll
    for (int j = 0; j < 4; ++j) {
      int col = j * 16 + l15;
      float bv = BIAS ? bias[col] : 0.f;
#pragma unroll
      for (int r = 0; r < 4; ++r) {
        int row = row0 + wrow0 + i * 16 + quad * 4 + r;
        if (row < M) {
          float v = acc[i][j][r] + bv;
          if (OUTBF)
            ((unsigned short*)Cv)[(size_t)row * 64 + col] = f2bf(v);
          else
            ((float*)Cv)[(size_t)row * 64 + col] = v;
        }
      }
    }
  }
}

// transpose-convert weights + zero the CSR count array (merged launch)
__global__ void trcvt_kernel(const float* __restrict__ W1, const float* __restrict__ W2,
                             unsigned short* __restrict__ W1t, unsigned short* __restrict__ W2t,
                             int* __restrict__ cnt, int n) {
  int id = blockIdx.x * blockDim.x + threadIdx.x;
  if (id < 65536) {
    int k = id & 255, nn = id >> 8;
    W1t[id] = f2bf(W1[k * 256 + nn]);
  } else {
    int id2 = id - 65536;
    int k = id2 & 255, nn = id2 >> 8;
    W2t[id2] = f2bf(W2[k * 64 + nn]);
  }
  if (id < n) cnt[id] = 0;
}

// ---------------------------------------------------------------------------
// CSR build — hierarchical scan
// ---------------------------------------------------------------------------
__global__ void count_kernel(const int* __restrict__ dst, int E, int* __restrict__ cnt) {
  int e = blockIdx.x * blockDim.x + threadIdx.x;
  if (e < E) atomicAdd(&cnt[dst[e]], 1);
}

__global__ __launch_bounds__(256) void scan_blocks(
    const int* __restrict__ cnt, int n, int* __restrict__ offs, int* __restrict__ bsum) {
  int t = threadIdx.x;
  int base = blockIdx.x * 1024 + t * 4;
  int4 v = make_int4(0, 0, 0, 0);
  if (base + 3 < n) {
    v = *(const int4*)(cnt + base);
  } else {
    if (base + 0 < n) v.x = cnt[base + 0];
    if (base + 1 < n) v.y = cnt[base + 1];
    if (base + 2 < n) v.z = cnt[base + 2];
  }
  int s = v.x + v.y + v.z + v.w;
  int lane = t & 63, w = t >> 6;
  int sc = s;
#pragma unroll
  for (int o = 1; o < 64; o <<= 1) {
    int u = __shfl_up(sc, o, 64);
    if (lane >= o) sc += u;
  }
  __shared__ int wsum[4];
  if (lane == 63) wsum[w] = sc;
  __syncthreads();
  int woff = 0;
#pragma unroll
  for (int i = 0; i < 4; ++i)
    if (i < w) woff += wsum[i];
  int excl = woff + sc - s;
  int o0 = excl, o1 = o0 + v.x, o2 = o1 + v.y, o3 = o2 + v.z;
  if (base + 3 < n) {
    *(int4*)(offs + base) = make_int4(o0, o1, o2, o3);
  } else {
    if (base + 0 < n) offs[base + 0] = o0;
    if (base + 1 < n) offs[base + 1] = o1;
    if (base + 2 < n) offs[base + 2] = o2;
  }
  if (t == 255) bsum[blockIdx.x] = woff + sc;
}

__global__ void scan_top(const int* __restrict__ bsum, int nb, int* __restrict__ boff,
                         int* __restrict__ offs, int n) {
  int lane = threadIdx.x;
  int s = (lane < nb) ? bsum[lane] : 0;
  int sc = s;
#pragma unroll
  for (int o = 1; o < 64; o <<= 1) {
    int u = __shfl_up(sc, o, 64);
    if (lane >= o) sc += u;
  }
  if (lane < nb) boff[lane] = sc - s;
  if (lane == 63) offs[n] = sc;
}

__global__ __launch_bounds__(256) void scan_add(
    int* __restrict__ offs, int* __restrict__ cur, const int* __restrict__ boff, int n) {
  int t = threadIdx.x;
  int base = blockIdx.x * 1024 + t * 4;
  int b = boff[blockIdx.x];
  if (base + 3 < n) {
    int4 v = *(const int4*)(offs + base);
    v.x += b; v.y += b; v.z += b; v.w += b;
    *(int4*)(offs + base) = v;
    *(int4*)(cur + base) = v;
  } else {
    for (int i = 0; i < 4; ++i)
      if (base + i < n) {
        int v = offs[base + i] + b;
        offs[base + i] = v;
        cur[base + i] = v;
      }
  }
}

__global__ void fill_kernel(const int* __restrict__ dst, const int* __restrict__ src, int E,
                            int* __restrict__ cur, int* __restrict__ csrc) {
  int e = blockIdx.x * blockDim.x + threadIdx.x;
  if (e < E) {
    int p = atomicAdd(&cur[dst[e]], 1);
    csrc[p] = src[e];
  }
}

// ---------------------------------------------------------------------------
// agg1 (R4-best): wave per dst node, no max-subtraction (logits bounded),
// pass A: denom + LDS weight stash; pass B: channel-parallel, unroll x4.
// ---------------------------------------------------------------------------
#define CAP1 80
__global__ __launch_bounds__(256) void agg1_kernel(
    const unsigned short* __restrict__ xp, const float* __restrict__ als,
    const float* __restrict__ ald, const int* __restrict__ offs,
    const int* __restrict__ csrc, const float* __restrict__ b1,
    unsigned short* __restrict__ hout, int nn) {
  __shared__ float ews[4][CAP1 * 4];
  int wv = threadIdx.x >> 6;
  int n = (blockIdx.x * blockDim.x + threadIdx.x) >> 6;
  int lane = threadIdx.x & 63;
  if (n >= nn) return;
  float4 aldn = *(const float4*)(ald + (size_t)n * 4);
  float4 alsn = *(const float4*)(als + (size_t)n * 4);
  float w0 = __expf(lrelu(alsn.x + aldn.x)), w1 = __expf(lrelu(alsn.y + aldn.y));
  float w2 = __expf(lrelu(alsn.z + aldn.z)), w3 = __expf(lrelu(alsn.w + aldn.w));
  int i0 = offs[n], i1 = offs[n + 1];

  float d0 = 0.f, d1 = 0.f, d2 = 0.f, d3 = 0.f;
  for (int i = i0 + lane; i < i1; i += 64) {
    int s = csrc[i];
    float4 a4 = *(const float4*)(als + (size_t)s * 4);
    float e0 = __expf(lrelu(a4.x + aldn.x));
    float e1 = __expf(lrelu(a4.y + aldn.y));
    float e2 = __expf(lrelu(a4.z + aldn.z));
    float e3 = __expf(lrelu(a4.w + aldn.w));
    d0 += e0; d1 += e1; d2 += e2; d3 += e3;
    int j = i - i0;
    if (j < CAP1) *(float4*)&ews[wv][j * 4] = make_float4(e0, e1, e2, e3);
  }
#pragma unroll
  for (int o = 32; o; o >>= 1) {
    d0 += __shfl_xor(d0, o, 64);
    d1 += __shfl_xor(d1, o, 64);
    d2 += __shfl_xor(d2, o, 64);
    d3 += __shfl_xor(d3, o, 64);
  }
  d0 += w0; d1 += w1; d2 += w2; d3 += w3;

  int h = lane >> 4;
  float selfw = (h == 0) ? w0 : (h == 1) ? w1 : (h == 2) ? w2 : w3;
  float invh = 1.f / ((h == 0) ? d0 : (h == 1) ? d1 : (h == 2) ? d2 : d3);
  float adh = (h == 0) ? aldn.x : (h == 1) ? aldn.y : (h == 2) ? aldn.z : aldn.w;

  uint2 v = *(const uint2*)(xp + (size_t)n * 256 + lane * 4);
  float a0 = selfw * bflo(v.x), a1 = selfw * bfhi(v.x);
  float a2 = selfw * bflo(v.y), a3 = selfw * bfhi(v.y);

  int lim = min(i1, i0 + CAP1);
  int i = i0;
  for (; i + 3 < lim; i += 4) {
    int j = i - i0;
    int sa = csrc[i], sb = csrc[i + 1], sc_ = csrc[i + 2], sd = csrc[i + 3];
    uint2 ua = *(const uint2*)(xp + (size_t)sa * 256 + lane * 4);
    uint2 ub = *(const uint2*)(xp + (size_t)sb * 256 + lane * 4);
    uint2 uc = *(const uint2*)(xp + (size_t)sc_ * 256 + lane * 4);
    uint2 ud = *(const uint2*)(xp + (size_t)sd * 256 + lane * 4);
    float wa = ews[wv][(j + 0) * 4 + h];
    float wb = ews[wv][(j + 1) * 4 + h];
    float wc = ews[wv][(j + 2) * 4 + h];
    float wd = ews[wv][(j + 3) * 4 + h];
    a0 += wa * bflo(ua.x) + wb * bflo(ub.x) + wc * bflo(uc.x) + wd * bflo(ud.x);
    a1 += wa * bfhi(ua.x) + wb * bfhi(ub.x) + wc * bfhi(uc.x) + wd * bfhi(ud.x);
    a2 += wa * bflo(ua.y) + wb * bflo(ub.y) + wc * bflo(uc.y) + wd * bflo(ud.y);
    a3 += wa * bfhi(ua.y) + wb * bfhi(ub.y) + wc * bfhi(uc.y) + wd * bfhi(ud.y);
  }
  for (; i < lim; ++i) {
    int sa = csrc[i];
    uint2 ua = *(const uint2*)(xp + (size_t)sa * 256 + lane * 4);
    float wa = ews[wv][(i - i0) * 4 + h];
    a0 += wa * bflo(ua.x); a1 += wa * bfhi(ua.x);
    a2 += wa * bflo(ua.y); a3 += wa * bfhi(ua.y);
  }
  for (; i < i1; ++i) {  // cold tail: deg > CAP1
    int sa = csrc[i];
    uint2 ua = *(const uint2*)(xp + (size_t)sa * 256 + lane * 4);
    float wa = __expf(lrelu(als[(size_t)sa * 4 + h] + adh));
    a0 += wa * bflo(ua.x); a1 += wa * bfhi(ua.x);
    a2 += wa * bflo(ua.y); a3 += wa * bfhi(ua.y);
  }
  float4 bb = *(const float4*)(b1 + lane * 4);
  float o0 = a0 * invh + bb.x, o1 = a1 * invh + bb.y;
  float o2 = a2 * invh + bb.z, o3 = a3 * invh + bb.w;
  o0 = o0 > 0.f ? o0 : __expf(o0) - 1.f;
  o1 = o1 > 0.f ? o1 : __expf(o1) - 1.f;
  o2 = o2 > 0.f ? o2 : __expf(o2) - 1.f;
  o3 = o3 > 0.f ? o3 : __expf(o3) - 1.f;
  uint2 p;
  p.x = (unsigned)f2bf(o0) | ((unsigned)f2bf(o1) << 16);
  p.y = (unsigned)f2bf(o2) | ((unsigned)f2bf(o3) << 16);
  *(uint2*)(hout + (size_t)n * 256 + lane * 4) = p;
}

// agg2 v5: 4 edges per wave-iteration — 16-lane groups, 8B/lane (4 ch);
// merge via shfl_xor(16)+(32); fuse +b2 +skip.
#define CAP2 128
__global__ __launch_bounds__(256) void agg2_kernel(
    const unsigned short* __restrict__ xp2, const float* __restrict__ als,
    const float* __restrict__ ald, const int* __restrict__ offs,
    const int* __restrict__ csrc, const float* __restrict__ b2,
    const float* __restrict__ skip, float* __restrict__ out, int nn) {
  __shared__ float ews[4][CAP2];
  int wv = threadIdx.x >> 6;
  int n = (blockIdx.x * blockDim.x + threadIdx.x) >> 6;
  int lane = threadIdx.x & 63;
  if (n >= nn) return;
  float aldn = ald[n];
  float selfw = __expf(lrelu(als[n] + aldn));
  int i0 = offs[n], i1 = offs[n + 1];

  float d = 0.f;
  for (int i = i0 + lane; i < i1; i += 64) {
    float e = __expf(lrelu(als[csrc[i]] + aldn));
    d += e;
    int j = i - i0;
    if (j < CAP2) ews[wv][j] = e;
  }
#pragma unroll
  for (int o = 32; o; o >>= 1) d += __shfl_xor(d, o, 64);
  d += selfw;
  float inv = 1.f / d;

  int grp = lane >> 4, l16 = lane & 15;
  uint2 sv = *(const uint2*)(xp2 + (size_t)n * 64 + l16 * 4);
  float sw = (grp == 0) ? selfw : 0.f;
  float a0 = sw * bflo(sv.x), a1 = sw * bfhi(sv.x);
  float a2 = sw * bflo(sv.y), a3 = sw * bfhi(sv.y);

  int lim = min(i1, i0 + CAP2);
  int i = i0 + grp;
  for (; i + 12 < lim; i += 16) {
    uint2 u[4];
    float wt[4];
#pragma unroll
    for (int q = 0; q < 4; ++q) {
      int s = csrc[i + q * 4];
      u[q] = *(const uint2*)(xp2 + (size_t)s * 64 + l16 * 4);
    }
#pragma unroll
    for (int q = 0; q < 4; ++q) wt[q] = ews[wv][i + q * 4 - i0];
#pragma unroll
    for (int q = 0; q < 4; ++q) {
      a0 += wt[q] * bflo(u[q].x); a1 += wt[q] * bfhi(u[q].x);
      a2 += wt[q] * bflo(u[q].y); a3 += wt[q] * bfhi(u[q].y);
    }
  }
  for (; i < lim; i += 4) {
    int s = csrc[i];
    uint2 u = *(const uint2*)(xp2 + (size_t)s * 64 + l16 * 4);
    float wt = ews[wv][i - i0];
    a0 += wt * bflo(u.x); a1 += wt * bfhi(u.x);
    a2 += wt * bflo(u.y); a3 += wt * bfhi(u.y);
  }
  for (; i < i1; i += 4) {  // cold tail
    int s = csrc[i];
    uint2 u = *(const uint2*)(xp2 + (size_t)s * 64 + l16 * 4);
    float wt = __expf(lrelu(als[s] + aldn));
    a0 += wt * bflo(u.x); a1 += wt * bfhi(u.x);
    a2 += wt * bflo(u.y); a3 += wt * bfhi(u.y);
  }
#pragma unroll
  for (int o = 16; o <= 32; o <<= 1) {
    a0 += __shfl_xor(a0, o, 64); a1 += __shfl_xor(a1, o, 64);
    a2 += __shfl_xor(a2, o, 64); a3 += __shfl_xor(a3, o, 64);
  }
  if (grp == 0) {
    float4 bb = *(const float4*)(b2 + l16 * 4);
    float4 sk = *(const float4*)(skip + (size_t)n * 64 + l16 * 4);
    float4 o4;
    o4.x = a0 * inv + bb.x + sk.x;
    o4.y = a1 * inv + bb.y + sk.y;
    o4.z = a2 * inv + bb.z + sk.z;
    o4.w = a3 * inv + bb.w + sk.w;
    *(float4*)(out + (size_t)n * 64 + l16 * 4) = o4;
  }
}

// ---------------------------------------------------------------------------
extern "C" void kernel_launch(void* const* d_in, const int* in_sizes, int n_in,
                              void* d_out, int out_size, void* d_ws, size_t ws_size,
                              hipStream_t stream) {
  const float* x_clean = (const float*)d_in[0];
  const float* x_noised = (const float*)d_in[1];
  const int* esrc = (const int*)d_in[2];
  const int* edst = (const int*)d_in[3];
  const float* W1 = (const float*)d_in[4];
  const float* a_src1 = (const float*)d_in[5];
  const float* a_dst1 = (const float*)d_in[6];
  const float* b1 = (const float*)d_in[7];
  const float* W2 = (const float*)d_in[8];
  const float* a_src2 = (const float*)d_in[9];
  const float* a_dst2 = (const float*)d_in[10];
  const float* b2 = (const float*)d_in[11];
  float* out = (float*)d_out;

  const int N = in_sizes[0] / 256;  // 50000
  const int E = in_sizes[2];        // 800000

  unsigned short* W1t = (unsigned short*)d_ws;      // 256*256
  unsigned short* W2t = W1t + 65536;                // 64*256
  unsigned short* xp1 = W2t + 16384;                // N*256 bf16
  unsigned short* hs = xp1 + (size_t)N * 256;       // N*256 bf16 (hs, then h)
  unsigned short* xp2 = hs + (size_t)N * 256;       // N*64 bf16
  float* skip = (float*)(xp2 + (size_t)N * 64);     // N*64 f32
  float* als1 = skip + (size_t)N * 64;              // N*4
  float* ald1 = als1 + (size_t)N * 4;               // N*4
  float* als2 = ald1 + (size_t)N * 4;               // N
  float* ald2 = als2 + N;                           // N
  int* cnt = (int*)(ald2 + N);                      // N
  int* offs = cnt + N;                              // N+1
  int* cur = offs + N + 1;                          // N
  int* csrc = cur + N;                              // E
  int* bsum = csrc + E;                             // <=64
  int* boff = bsum + 64;                            // <=64

  const int gemm_rows = (N + 127) / 128;  // 391
  dim3 block256(256);
  const int wave_grid = (N * 64 + 255) / 256;  // 12500
  const int edge_grid = (E + 255) / 256;
  const int nb = (N + 1023) / 1024;

  // weights transpose+convert, fused with cnt zeroing
  hipLaunchKernelGGL(trcvt_kernel, dim3((65536 + 16384) / 256), block256, 0, stream,
                     W1, W2, W1t, W2t, cnt, N);
  // xp1 = x_noised @ W1 (bf16 out) + fused al1
  hipLaunchKernelGGL((gemm256<false, false, true>), dim3(gemm_rows), block256, 0, stream,
                     x_noised, W1t, nullptr, xp1, N, a_src1, a_dst1, als1, ald1);
  // hs = relu(x_clean @ W1 + b1)
  hipLaunchKernelGGL((gemm256<true, true, false>), dim3(gemm_rows), block256, 0, stream,
                     x_clean, W1t, b1, hs, N, nullptr, nullptr, nullptr, nullptr);
  // skip = hs @ W2 + b2 (fp32 out)
  hipLaunchKernelGGL((gemm64<true, false, false>), dim3(gemm_rows), block256, 0, stream,
                     hs, W2t, b2, skip, N, nullptr, nullptr, nullptr, nullptr);
  // CSR build
  hipLaunchKernelGGL(count_kernel, dim3(edge_grid), block256, 0, stream, edst, E, cnt);
  hipLaunchKernelGGL(scan_blocks, dim3(nb), block256, 0, stream, cnt, N, offs, bsum);
  hipLaunchKernelGGL(scan_top, dim3(1), dim3(64), 0, stream, bsum, nb, boff, offs, N);
  hipLaunchKernelGGL(scan_add, dim3(nb), block256, 0, stream, offs, cur, boff, N);
  hipLaunchKernelGGL(fill_kernel, dim3(edge_grid), block256, 0, stream, edst, esrc, E, cur, csrc);
  // layer-1 aggregation -> h
  hipLaunchKernelGGL(agg1_kernel, dim3(wave_grid), block256, 0, stream,
                     xp1, als1, ald1, offs, csrc, b1, hs, N);
  // xp2 = h @ W2 (bf16 out) + fused al2
  hipLaunchKernelGGL((gemm64<false, true, true>), dim3(gemm_rows), block256, 0, stream,
                     hs, W2t, nullptr, xp2, N, a_src2, a_dst2, als2, ald2);
  // layer-2 aggregation + b2 + skip -> out
  hipLaunchKernelGGL(agg2_kernel, dim3(wave_grid), block256, 0, stream,
                     xp2, als2, ald2, offs, csrc, b2, skip, out, N);
}